// Round 2
// baseline (236.135 us; speedup 1.0000x reference)
//
#include <hip/hip_runtime.h>

// Forward-fill imputation (SIMPLE.imputate), fused single-kernel version.
//   observed = mask < 0.9
//   gather_idx[b,n] = most recent observed pos <= n (wrap-around to row's last
//                     observed for leading missing; 0 if row has none)
//   out[b,n,:] = in[b, gather_idx[b,n], :]
//
// B=64, N=4096, D=128 fp32. Pure memory-bound: ~134MB write + ~121MB read.
// Strategy: 32 blocks per batch row. Each block redundantly computes the full
// row scan (mask row = 16KB, L2-resident -> redundancy is ~free in HBM terms),
// keeps gather indices in LDS, then copies its 128-row output slice as float4.
// Single dispatch, no workspace, no cross-kernel dependency.

#define FF_N 4096
#define FF_D 128
#define SLICES 32                 // blocks per batch row
#define SLICE_N (FF_N / SLICES)   // 128 n-positions per block

__global__ __launch_bounds__(256) void ffill_fused(const float4* __restrict__ in,
                                                   const float* __restrict__ mask,
                                                   float4* __restrict__ out) {
    const int b   = blockIdx.x >> 5;   // batch row
    const int s   = blockIdx.x & 31;   // slice within row
    const int tid = threadIdx.x;

    __shared__ int gidx[FF_N];         // 16 KB: resolved gather index per n
    __shared__ int scanbuf[256];       // Hillis-Steele buffer

    // ---- Phase A: redundant per-row forward-fill scan (all 256 threads) ----
    const float* m = mask + (size_t)b * FF_N;
    const int base = tid * 16;         // 16 contiguous mask elems per thread

    float4 mv[4];
    const float4* m4 = reinterpret_cast<const float4*>(m + base);
#pragma unroll
    for (int k = 0; k < 4; ++k) mv[k] = m4[k];

    unsigned obsbits = 0;
    int segmax = -1;
#pragma unroll
    for (int k = 0; k < 4; ++k) {
        const float vals[4] = {mv[k].x, mv[k].y, mv[k].z, mv[k].w};
#pragma unroll
        for (int j = 0; j < 4; ++j) {
            const int idx = k * 4 + j;
            const bool o = vals[j] < 0.9f;     // observed
            obsbits |= (unsigned)o << idx;
            if (o) segmax = base + idx;
        }
    }

    // 256-wide inclusive max-scan of per-thread segment maxima.
    scanbuf[tid] = segmax;
    __syncthreads();
    int v = segmax;
#pragma unroll
    for (int off = 1; off < 256; off <<= 1) {
        const int t = (tid >= off) ? scanbuf[tid - off] : -1;
        __syncthreads();
        v = max(v, t);
        scanbuf[tid] = v;
        __syncthreads();
    }
    const int prefix   = tid ? scanbuf[tid - 1] : -1;  // exclusive prefix
    const int total    = scanbuf[255];                 // row's last observed idx
    const int fallback = (total < 0) ? 0 : total;      // row w/o observed -> 0

    // Serial forward fill within my 16 elements; results into LDS.
    int last = prefix;
    int outv[16];
#pragma unroll
    for (int k = 0; k < 16; ++k) {
        if ((obsbits >> k) & 1u) last = base + k;
        outv[k] = (last < 0) ? fallback : last;
    }
    int4* g4 = reinterpret_cast<int4*>(&gidx[base]);
#pragma unroll
    for (int k = 0; k < 4; ++k)
        g4[k] = make_int4(outv[4 * k], outv[4 * k + 1], outv[4 * k + 2], outv[4 * k + 3]);
    __syncthreads();

    // ---- Phase B: gather-copy my 128-row slice, float4 granularity ----
    // Slice = SLICE_N rows x 32 float4 = 4096 float4 = 16 passes of 256 thr.
    const size_t rowbase = (size_t)b * FF_N * (FF_D / 4);
    const float4* inb  = in  + rowbase;
    float4*       outb = out + rowbase + (size_t)s * SLICE_N * (FF_D / 4);
    const int nbase = s * SLICE_N;

#pragma unroll
    for (int p = 0; p < 16; ++p) {
        const int q    = p * 256 + tid;
        const int nloc = q >> 5;                 // local n within slice
        const int l    = q & 31;                 // float4 lane within D
        const int gi   = gidx[nbase + nloc];     // LDS broadcast (2 addrs/wave)
        outb[q] = inb[(size_t)gi * (FF_D / 4) + l];
    }
}

extern "C" void kernel_launch(void* const* d_in, const int* in_sizes, int n_in,
                              void* d_out, int out_size, void* d_ws, size_t ws_size,
                              hipStream_t stream) {
    const float* inp  = (const float*)d_in[0];   // [B, N, D] fp32
    const float* mask = (const float*)d_in[1];   // [B, N]    fp32
    float* out = (float*)d_out;

    const int B = in_sizes[1] / FF_N;            // 64
    ffill_fused<<<B * SLICES, 256, 0, stream>>>(
        (const float4*)inp, mask, (float4*)out);
}